// Round 6
// baseline (110.456 us; speedup 1.0000x reference)
//
#include <hip/hip_runtime.h>
#include <hip/hip_cooperative_groups.h>
#include <math.h>

namespace cg = cooperative_groups;

#define NN 256
#define BATCH 64
#define PB 4
#define NB (BATCH + PB)     // 68 slabs (64 real + 4 identity pseudo-slabs)
#define KMAX 4              // moments m_0..m_4 (tail ~1e-5 in afe, thresh 3.6e-2)
#define NM (KMAX + 1)
#define NSTEPS (KMAX / 2)   // 2 chain steps
#define CGRP 2              // column groups per slab
#define CW 32               // columns per group
#define YSTR 264            // LDS k-stride (528B row -> 2-way bank alias = free)
#define NPART 8             // partials per (slab, moment): 2 groups x 4 waves
#define NBLK (CGRP * NB)    // 136 blocks

using short8 = __attribute__((ext_vector_type(8))) short;
using us4    = __attribute__((ext_vector_type(4))) unsigned short;
using f32x4  = __attribute__((ext_vector_type(4))) float;

__device__ __forceinline__ float bf2f(unsigned short u) {
    union { unsigned int i; float f; } v; v.i = ((unsigned int)u) << 16; return v.f;
}
__device__ __forceinline__ unsigned short f2bf(float f) {
    union { float f; unsigned int i; } v; v.f = f;
    unsigned int b = v.i;
    return (unsigned short)((b + 0x7FFFu + ((b >> 16) & 1u)) >> 16);
}

// ---------------------------------------------------------------------------
// Single cooperative kernel:
//   Phase A: build Jsym = bf16(0.5*(Jr+Jr^T), zero diag) cooperatively.
//   Phase B: per (column-group, slab) block: 2 steps y <- Jsym*y with MFMA
//            (J A-fragments in 128 VGPRs, y in LDS ping-pong), fused fp32
//            dots m_{2j-1}=<y_{j-1},y_j>, m_{2j}=<y_j,y_j>; m0=||x||^2.
//   Phase C: block 0 reduces partials and runs the gated Newton + phi/afe.
// ---------------------------------------------------------------------------
__global__ __launch_bounds__(256, 1)
void fused_kernel(const float* __restrict__ Jr,
                  const float* __restrict__ x,
                  unsigned short* __restrict__ Jsym,
                  float* __restrict__ partial,
                  float* __restrict__ out) {
    cg::grid_group grid = cg::this_grid();
    __shared__ unsigned short ybuf[2][CW][YSTR];
    __shared__ float msum[NB * NM];

    const int g = blockIdx.x;          // 0..CGRP-1
    const int b = blockIdx.y;          // 0..67
    const int bid = b * CGRP + g;      // 0..135
    const int t = threadIdx.x;
    const int w = t >> 6;
    const int lane = t & 63;
    const int quad = lane >> 4;
    const int l15 = lane & 15;

    // ---------------- Phase A: jbuild (coalesced row read + col gather) ----
    for (int i = bid * 256 + t; i < NN * NN; i += NBLK * 256) {
        int r = i >> 8, c = i & 255;
        float v = (r == c) ? 0.0f : 0.5f * (Jr[i] + Jr[(c << 8) + r]);
        Jsym[i] = f2bf(v);
    }
    grid.sync();

    // ---------------- Phase B: chain -------------------------------------
    // J A-fragments into registers (once): wave w owns rows w*64..w*64+63
    short8 afr[4][8];
#pragma unroll
    for (int mt = 0; mt < 4; ++mt)
#pragma unroll
        for (int kc = 0; kc < 8; ++kc)
            afr[mt][kc] = *(const short8*)(Jsym + ((w * 64 + mt * 16 + l15) << 8)
                                                + kc * 32 + quad * 8);

    // y0 into ybuf[0]; fused fp32 m0 partial for real slabs
    if (b < BATCH) {
        const float* xb = x + (b << 14) + g * CW;    // x[b][k][g*32..]
        float s0 = 0.f;
#pragma unroll
        for (int it = 0; it < 8; ++it) {
            int k = it * 32 + (t >> 3);
            int nn = (t & 7) * 4;
            float4 v = *(const float4*)(xb + (k << 6) + nn);
            s0 += v.x * v.x + v.y * v.y + v.z * v.z + v.w * v.w;
            ybuf[0][nn + 0][k] = f2bf(v.x);
            ybuf[0][nn + 1][k] = f2bf(v.y);
            ybuf[0][nn + 2][k] = f2bf(v.z);
            ybuf[0][nn + 3][k] = f2bf(v.w);
        }
#pragma unroll
        for (int o = 32; o > 0; o >>= 1) s0 += __shfl_down(s0, o);
        if (lane == 0) partial[(b * NM + 0) * NPART + g * 4 + w] = s0;
    } else {
        int p = b - BATCH;
        for (int i = t; i < CW * 256; i += 256) ybuf[0][i >> 8][i & 255] = 0;
        __syncthreads();
        if (t < CW) ybuf[0][t][p * 64 + g * CW + t] = 0x3F80;  // e_{p*64+g*32+t}
        if (t < NPART) partial[((b)*NM + 0) * NPART + t] = 0.f; // unused, keep clean
    }
    __syncthreads();

    int cur = 0;
    for (int j = 1; j <= NSTEPS; ++j) {
        f32x4 acc[4][2] = {};
#pragma unroll
        for (int kc = 0; kc < 8; ++kc) {
            short8 bfr[2];
#pragma unroll
            for (int nt = 0; nt < 2; ++nt)
                bfr[nt] = *(const short8*)&ybuf[cur][nt * 16 + l15][kc * 32 + quad * 8];
#pragma unroll
            for (int mt = 0; mt < 4; ++mt)
#pragma unroll
                for (int nt = 0; nt < 2; ++nt)
                    acc[mt][nt] = __builtin_amdgcn_mfma_f32_16x16x32_bf16(
                        afr[mt][kc], bfr[nt], acc[mt][nt], 0, 0, 0);
        }

        const int nxt = cur ^ 1;
        float d1 = 0.f, d2 = 0.f;
#pragma unroll
        for (int mt = 0; mt < 4; ++mt) {
            int mbase = w * 64 + mt * 16 + quad * 4;   // rows are k-contiguous
#pragma unroll
            for (int nt = 0; nt < 2; ++nt) {
                int col = nt * 16 + l15;
                us4 prev = *(const us4*)&ybuf[cur][col][mbase];
                us4 outv;
#pragma unroll
                for (int r = 0; r < 4; ++r) {
                    float v = acc[mt][nt][r];
                    d1 += bf2f(prev[r]) * v;
                    d2 += v * v;
                    outv[r] = f2bf(v);
                }
                *(us4*)&ybuf[nxt][col][mbase] = outv;
            }
        }
#pragma unroll
        for (int o = 32; o > 0; o >>= 1) {
            d1 += __shfl_down(d1, o);
            d2 += __shfl_down(d2, o);
        }
        if (lane == 0) {
            partial[(b * NM + 2 * j - 1) * NPART + g * 4 + w] = d1;
            partial[(b * NM + 2 * j    ) * NPART + g * 4 + w] = d2;
        }
        cur = nxt;
        __syncthreads();
    }

    grid.sync();

    // ---------------- Phase C: block 0 reduces + solves --------------------
    if (bid != 0) return;

    for (int pr = t; pr < NB * NM; pr += 256) {
        float s = 0.f;
#pragma unroll
        for (int i = 0; i < NPART; ++i) s += partial[pr * NPART + i];
        msum[pr] = s;
    }
    __syncthreads();

    if (t < BATCH) {
        const int bb = t;
        float mk[NM], Tk[NM];
        Tk[0] = 256.0f;
#pragma unroll
        for (int k = 0; k < NM; ++k) {
            mk[k] = msum[bb * NM + k];
            if (k >= 1) {
                float tv = 0.f;
                for (int p = 0; p < PB; ++p) tv += msum[(BATCH + p) * NM + k];
                Tk[k] = tv;
            }
        }
        float tt = 1.0f;
        for (int it = 0; it < 40; ++it) {
            float inv = 1.0f / tt;
            float p1 = inv, S1 = 0.f, S1d = 0.f, S3 = 0.f, S3d = 0.f;
#pragma unroll
            for (int k = 0; k < NM; ++k) {
                float p2 = p1 * inv;
                float p3 = p2 * inv;
                float kp1 = (float)(k + 1);
                S1  += Tk[k] * p1;
                S1d += kp1 * Tk[k] * p2;
                S3  += kp1 * mk[k] * p2;
                S3d += kp1 * (float)(k + 2) * mk[k] * p3;
                p1 = p2;
            }
            float f  = 256.0f - 0.5f * S1 - S3 * (1.0f / 256.0f);
            float df = 0.5f * S1d + S3d * (1.0f / 256.0f);
            if (fabsf(f) <= 1e-4f) break;
            tt -= f / df;
        }
        float inv = 1.0f / tt;
        float logdet = 256.0f * logf(tt);
        float quad = 0.f;
        float p1 = inv, pk = 1.0f;
#pragma unroll
        for (int k = 0; k < NM; ++k) {
            quad += mk[k] * p1;
            if (k >= 1) { pk *= inv; logdet -= Tk[k] / (float)k * pk; }
            p1 *= inv;
        }
        float phi = 256.0f * tt - 0.5f * logdet + quad * (1.0f / 256.0f);
        float afe = -(0.5f * logf((float)M_PI) + phi * (1.0f / 256.0f));
        out[bb] = afe;
        out[BATCH + bb] = tt;
    }
}

// ---------------------------------------------------------------------------
extern "C" void kernel_launch(void* const* d_in, const int* in_sizes, int n_in,
                              void* d_out, int out_size, void* d_ws, size_t ws_size,
                              hipStream_t stream) {
    const float* x  = (const float*)d_in[0];
    const float* Jr = (const float*)d_in[1];
    float* out = (float*)d_out;

    char* base = (char*)d_ws;
    unsigned short* Jsym = (unsigned short*)base;        // 128 KB
    float* partial = (float*)(base + 131072);            // 68*5*8 floats

    void* args[] = { (void*)&Jr, (void*)&x, (void*)&Jsym, (void*)&partial, (void*)&out };
    hipLaunchCooperativeKernel((const void*)fused_kernel,
                               dim3(CGRP, NB), dim3(256), args, 0, stream);
}

// Round 7
// 104.870 us; speedup vs baseline: 1.0533x; 1.0533x over previous
//
#include <hip/hip_runtime.h>
#include <math.h>

#define NN 256
#define BATCH 64
#define PB 4
#define NB (BATCH + PB)     // 68 slabs (64 real + 4 identity pseudo-slabs)
#define KMAX 4              // moments m_0..m_4 (tail ~1e-5 in afe, thresh 3.6e-2)
#define NM (KMAX + 1)
#define NSTEPS (KMAX / 2)   // 2 chain steps
#define CGRP 2              // column groups per slab
#define CW 32               // columns per group
#define YSTR 266            // LDS k-stride: 133 dwords = 5 mod 32 -> conflict-free cols
#define NPART 8             // partials per (slab, moment): 2 groups x 4 waves
#define NBLK (CGRP * NB)    // 136 blocks

using short8 = __attribute__((ext_vector_type(8))) short;
using us4    = __attribute__((ext_vector_type(4))) unsigned short;
using f32x4  = __attribute__((ext_vector_type(4))) float;

__device__ __forceinline__ float bf2f(unsigned short u) {
    union { unsigned int i; float f; } v; v.i = ((unsigned int)u) << 16; return v.f;
}
__device__ __forceinline__ unsigned short f2bf(float f) {
    union { float f; unsigned int i; } v; v.f = f;
    unsigned int b = v.i;
    return (unsigned short)((b + 0x7FFFu + ((b >> 16) & 1u)) >> 16);
}

// ---------------------------------------------------------------------------
// Single ordinary (non-cooperative) dispatch, 136 blocks x 256 threads:
//   Phase 1: each wave builds its J A-fragments (rows w*64..w*64+63, bf16,
//            symmetrized 0.5*(Jr+Jr^T), zero diag) straight from Jr into
//            128 VGPRs. No Jsym buffer, no grid sync.
//   Phase 2: 2 chain steps y <- J*y (y = 32 columns in LDS ping-pong, MFMA
//            16x16x32 bf16), fused fp32 dots m_{2j-1}=<y_{j-1},y_j>,
//            m_{2j}=<y_j,y_j>; m0=||x||^2 fused into the y0 load.
//   Phase 3: per-block partials stored; fence + release flag. Block 0 spins
//            on all 136 flags (poisoned !=1 at entry each launch), acquires,
//            reduces, runs the gated Newton + phi/afe, writes out.
// ---------------------------------------------------------------------------
__global__ __launch_bounds__(256, 1)
void fused_kernel(const float* __restrict__ Jr,
                  const float* __restrict__ x,
                  float* __restrict__ partial,
                  unsigned int* __restrict__ flags,
                  float* __restrict__ out) {
    __shared__ unsigned short ybuf[2][CW][YSTR];
    __shared__ float msum[NB * NM];

    const int g = blockIdx.x;          // 0..CGRP-1
    const int b = blockIdx.y;          // 0..67
    const int bid = b * CGRP + g;      // 0..135
    const int t = threadIdx.x;
    const int w = t >> 6;
    const int lane = t & 63;
    const int quad = lane >> 4;
    const int l15 = lane & 15;

    // ---------------- Phase 1: J A-fragments from Jr (per block) ----------
    short8 afr[4][8];
#pragma unroll
    for (int mt = 0; mt < 4; ++mt) {
        const int r = w * 64 + mt * 16 + l15;
        const float* Jrow = Jr + (r << 8);
#pragma unroll
        for (int kc = 0; kc < 8; ++kc) {
            const int kb = kc * 32 + quad * 8;
            float4 a0 = *(const float4*)(Jrow + kb);
            float4 a1 = *(const float4*)(Jrow + kb + 4);
            float d[8] = {a0.x, a0.y, a0.z, a0.w, a1.x, a1.y, a1.z, a1.w};
            short8 frag;
#pragma unroll
            for (int j = 0; j < 8; ++j) {
                const int k = kb + j;
                float tv = Jr[(k << 8) + r];
                float v = (k == r) ? 0.0f : 0.5f * (d[j] + tv);
                frag[j] = (short)f2bf(v);
            }
            afr[mt][kc] = frag;
        }
    }

    // ---------------- Phase 2: y0 load (+ fused m0), then 2 chain steps ----
    if (b < BATCH) {
        const float* xb = x + (b << 14) + g * CW;    // x[b][k][g*32..]
        float s0 = 0.f;
#pragma unroll
        for (int it = 0; it < 8; ++it) {
            int k = it * 32 + (t >> 3);
            int nn = (t & 7) * 4;
            float4 v = *(const float4*)(xb + (k << 6) + nn);
            s0 += v.x * v.x + v.y * v.y + v.z * v.z + v.w * v.w;
            ybuf[0][nn + 0][k] = f2bf(v.x);
            ybuf[0][nn + 1][k] = f2bf(v.y);
            ybuf[0][nn + 2][k] = f2bf(v.z);
            ybuf[0][nn + 3][k] = f2bf(v.w);
        }
#pragma unroll
        for (int o = 32; o > 0; o >>= 1) s0 += __shfl_down(s0, o);
        if (lane == 0) partial[(b * NM + 0) * NPART + g * 4 + w] = s0;
    } else {
        int p = b - BATCH;
        for (int i = t; i < CW * 256; i += 256) ybuf[0][i >> 8][i & 255] = 0;
        __syncthreads();
        if (t < CW) ybuf[0][t][p * 64 + g * CW + t] = 0x3F80;  // e_{p*64+g*32+t}
        if (t < NPART) partial[(b * NM + 0) * NPART + t] = 0.f;
    }
    __syncthreads();

    int cur = 0;
    for (int j = 1; j <= NSTEPS; ++j) {
        f32x4 acc[4][2] = {};
#pragma unroll
        for (int kc = 0; kc < 8; ++kc) {
            short8 bfr[2];
#pragma unroll
            for (int nt = 0; nt < 2; ++nt)
                bfr[nt] = *(const short8*)&ybuf[cur][nt * 16 + l15][kc * 32 + quad * 8];
#pragma unroll
            for (int mt = 0; mt < 4; ++mt)
#pragma unroll
                for (int nt = 0; nt < 2; ++nt)
                    acc[mt][nt] = __builtin_amdgcn_mfma_f32_16x16x32_bf16(
                        afr[mt][kc], bfr[nt], acc[mt][nt], 0, 0, 0);
        }

        const int nxt = cur ^ 1;
        float d1 = 0.f, d2 = 0.f;
#pragma unroll
        for (int mt = 0; mt < 4; ++mt) {
            int mbase = w * 64 + mt * 16 + quad * 4;   // rows are k-contiguous
#pragma unroll
            for (int nt = 0; nt < 2; ++nt) {
                int col = nt * 16 + l15;
                us4 prev = *(const us4*)&ybuf[cur][col][mbase];
                us4 outv;
#pragma unroll
                for (int r = 0; r < 4; ++r) {
                    float v = acc[mt][nt][r];
                    d1 += bf2f(prev[r]) * v;
                    d2 += v * v;
                    outv[r] = f2bf(v);
                }
                *(us4*)&ybuf[nxt][col][mbase] = outv;
            }
        }
#pragma unroll
        for (int o = 32; o > 0; o >>= 1) {
            d1 += __shfl_down(d1, o);
            d2 += __shfl_down(d2, o);
        }
        if (lane == 0) {
            partial[(b * NM + 2 * j - 1) * NPART + g * 4 + w] = d1;
            partial[(b * NM + 2 * j    ) * NPART + g * 4 + w] = d2;
        }
        cur = nxt;
        __syncthreads();
    }

    // ---------------- Phase 3: publish; block 0 consumes + solves ----------
    __threadfence();   // make partial stores visible device-wide
    if (t == 0)
        __hip_atomic_store(&flags[bid], 1u, __ATOMIC_RELEASE, __HIP_MEMORY_SCOPE_AGENT);
    if (bid != 0) return;

    // spin until all 136 blocks have published (flags poisoned !=1 at entry)
    for (int i = t; i < NBLK; i += 256)
        while (__hip_atomic_load(&flags[i], __ATOMIC_RELAXED, __HIP_MEMORY_SCOPE_AGENT) != 1u) {}
    __syncthreads();
    __threadfence();   // acquire: invalidate stale cache lines for partial

    for (int pr = t; pr < NB * NM; pr += 256) {
        float s = 0.f;
#pragma unroll
        for (int i = 0; i < NPART; ++i) s += partial[pr * NPART + i];
        msum[pr] = s;
    }
    __syncthreads();

    if (t < BATCH) {
        const int bb = t;
        float mk[NM], Tk[NM];
        Tk[0] = 256.0f;
#pragma unroll
        for (int k = 0; k < NM; ++k) {
            mk[k] = msum[bb * NM + k];
            if (k >= 1) {
                float tv = 0.f;
                for (int p = 0; p < PB; ++p) tv += msum[(BATCH + p) * NM + k];
                Tk[k] = tv;
            }
        }
        float tt = 1.0f;
        for (int it = 0; it < 40; ++it) {
            float inv = 1.0f / tt;
            float p1 = inv, S1 = 0.f, S1d = 0.f, S3 = 0.f, S3d = 0.f;
#pragma unroll
            for (int k = 0; k < NM; ++k) {
                float p2 = p1 * inv;
                float p3 = p2 * inv;
                float kp1 = (float)(k + 1);
                S1  += Tk[k] * p1;
                S1d += kp1 * Tk[k] * p2;
                S3  += kp1 * mk[k] * p2;
                S3d += kp1 * (float)(k + 2) * mk[k] * p3;
                p1 = p2;
            }
            float f  = 256.0f - 0.5f * S1 - S3 * (1.0f / 256.0f);
            float df = 0.5f * S1d + S3d * (1.0f / 256.0f);
            if (fabsf(f) <= 1e-4f) break;
            tt -= f / df;
        }
        float inv = 1.0f / tt;
        float logdet = 256.0f * logf(tt);
        float quad = 0.f;
        float p1 = inv, pk = 1.0f;
#pragma unroll
        for (int k = 0; k < NM; ++k) {
            quad += mk[k] * p1;
            if (k >= 1) { pk *= inv; logdet -= Tk[k] / (float)k * pk; }
            p1 *= inv;
        }
        float phi = 256.0f * tt - 0.5f * logdet + quad * (1.0f / 256.0f);
        float afe = -(0.5f * logf((float)M_PI) + phi * (1.0f / 256.0f));
        out[bb] = afe;
        out[BATCH + bb] = tt;
    }
}

// ---------------------------------------------------------------------------
extern "C" void kernel_launch(void* const* d_in, const int* in_sizes, int n_in,
                              void* d_out, int out_size, void* d_ws, size_t ws_size,
                              hipStream_t stream) {
    const float* x  = (const float*)d_in[0];
    const float* Jr = (const float*)d_in[1];
    float* out = (float*)d_out;

    float* partial = (float*)d_ws;                       // 68*5*8 floats
    unsigned int* flags = (unsigned int*)(partial + NB * NM * NPART);  // 136 u32

    fused_kernel<<<dim3(CGRP, NB), 256, 0, stream>>>(Jr, x, partial, flags, out);
}

// Round 8
// 78.228 us; speedup vs baseline: 1.4120x; 1.3406x over previous
//
#include <hip/hip_runtime.h>
#include <math.h>

#define NN 256
#define BATCH 64
#define PB 4
#define NB (BATCH + PB)     // 68 slabs (64 real + 4 identity pseudo-slabs)
#define KMAX 4              // moments m_0..m_4 (tail ~1e-5 in afe, thresh 3.6e-2)
#define NM (KMAX + 1)
#define NSTEPS (KMAX / 2)   // 2 chain steps
#define CGRP 2              // column groups per slab
#define CW 32               // columns per group
#define YSTR 264            // LDS k-stride: 528B rows, 16B-aligned, 2-way banks (free)
#define NPART 8             // partials per (slab, moment): 2 groups x 4 waves
#define NBLK (CGRP * NB)    // 136 blocks
#define JROWS 16            // output rows per jbuild block
#define JBLK (NN / JROWS)   // 16 jbuild blocks

using short8 = __attribute__((ext_vector_type(8))) short;
using us4    = __attribute__((ext_vector_type(4))) unsigned short;
using f32x4  = __attribute__((ext_vector_type(4))) float;

__device__ __forceinline__ float bf2f(unsigned short u) {
    union { unsigned int i; float f; } v; v.i = ((unsigned int)u) << 16; return v.f;
}
__device__ __forceinline__ unsigned short f2bf(float f) {
    union { float f; unsigned int i; } v; v.f = f;
    unsigned int b = v.i;
    return (unsigned short)((b + 0x7FFFu + ((b >> 16) & 1u)) >> 16);
}

// ---------------------------------------------------------------------------
// jbuild: Jsym = bf16( Jr + Jr^T ), diag zeroed  (NOTE: no 0.5 — the solve
// rescales moments by 2^-k). Block I emits rows [I*16, I*16+16).
// Transposed operand comes from an LDS-staged 256x16 column slice loaded
// with coalesced float4 reads — no uncoalesced global access.
// ---------------------------------------------------------------------------
__global__ __launch_bounds__(256)
void jbuild_kernel(const float* __restrict__ Jr,
                   unsigned short* __restrict__ Jsym) {
    __shared__ unsigned short S[NN][JROWS + 2];   // S[c][j] = bf16(Jr[c][I*16+j])
    const int I = blockIdx.x;
    const int t = threadIdx.x;

    // stage column slice (coalesced: 4 lanes x 16B per row, 64 rows per iter)
    {
        const int c0 = t >> 2;          // 0..63
        const int j4 = (t & 3) * 4;     // 0,4,8,12
        for (int cc = 0; cc < 4; ++cc) {
            int c = cc * 64 + c0;
            float4 v = *(const float4*)(Jr + (c << 8) + I * JROWS + j4);
            S[c][j4 + 0] = f2bf(v.x);
            S[c][j4 + 1] = f2bf(v.y);
            S[c][j4 + 2] = f2bf(v.z);
            S[c][j4 + 3] = f2bf(v.w);
        }
    }
    __syncthreads();

    // emit rows r = I*16 + dr: Jsym[r][c] = Jr[r][c] + Jr[c][r], diag 0
    const int dr = t >> 4;              // 0..15
    const int r = I * JROWS + dr;
    const int c4 = (t & 15) * 4;        // 0..60
    const float* Jrow = Jr + (r << 8);
    for (int cc = 0; cc < 4; ++cc) {
        int c = cc * 64 + c4;
        float4 v = *(const float4*)(Jrow + c);
        float s0 = v.x + bf2f(S[c + 0][dr]);
        float s1 = v.y + bf2f(S[c + 1][dr]);
        float s2 = v.z + bf2f(S[c + 2][dr]);
        float s3 = v.w + bf2f(S[c + 3][dr]);
        if (c + 0 == r) s0 = 0.f;
        if (c + 1 == r) s1 = 0.f;
        if (c + 2 == r) s2 = 0.f;
        if (c + 3 == r) s3 = 0.f;
        us4 o;
        o[0] = f2bf(s0); o[1] = f2bf(s1); o[2] = f2bf(s2); o[3] = f2bf(s3);
        *(us4*)(Jsym + (r << 8) + c) = o;
    }
}

// ---------------------------------------------------------------------------
// chain_solve: 136 blocks. Per (column-group, slab) block: J A-fragments via
// 32 coalesced b128 loads from Jsym into 128 VGPRs; y (32 cols) in LDS
// ping-pong; 2 MFMA chain steps with fused fp32 dots. Then flag-publish;
// block 0 spins (flags poisoned !=1 at entry), reduces, runs the gated
// Newton (+2^-k rescale) and phi/afe.
// ---------------------------------------------------------------------------
__global__ __launch_bounds__(256, 1)
void chain_solve_kernel(const unsigned short* __restrict__ Jsym,
                        const float* __restrict__ x,
                        float* __restrict__ partial,
                        unsigned int* __restrict__ flags,
                        float* __restrict__ out) {
    __shared__ unsigned short ybuf[2][CW][YSTR];
    __shared__ float msum[NB * NM];

    const int g = blockIdx.x;          // 0..CGRP-1
    const int b = blockIdx.y;          // 0..67
    const int bid = b * CGRP + g;      // 0..135
    const int t = threadIdx.x;
    const int w = t >> 6;
    const int lane = t & 63;
    const int quad = lane >> 4;
    const int l15 = lane & 15;

    // ---- J A-fragments (coalesced b128 from L2) ----
    short8 afr[4][8];
#pragma unroll
    for (int mt = 0; mt < 4; ++mt)
#pragma unroll
        for (int kc = 0; kc < 8; ++kc)
            afr[mt][kc] = *(const short8*)(Jsym + ((w * 64 + mt * 16 + l15) << 8)
                                                + kc * 32 + quad * 8);

    // ---- y0 into ybuf[0]; fused fp32 m0 partial for real slabs ----
    if (b < BATCH) {
        const float* xb = x + (b << 14) + g * CW;    // x[b][k][g*32..]
        float s0 = 0.f;
#pragma unroll
        for (int it = 0; it < 8; ++it) {
            int k = it * 32 + (t >> 3);
            int nn = (t & 7) * 4;
            float4 v = *(const float4*)(xb + (k << 6) + nn);
            s0 += v.x * v.x + v.y * v.y + v.z * v.z + v.w * v.w;
            ybuf[0][nn + 0][k] = f2bf(v.x);
            ybuf[0][nn + 1][k] = f2bf(v.y);
            ybuf[0][nn + 2][k] = f2bf(v.z);
            ybuf[0][nn + 3][k] = f2bf(v.w);
        }
#pragma unroll
        for (int o = 32; o > 0; o >>= 1) s0 += __shfl_down(s0, o);
        if (lane == 0) partial[(b * NM + 0) * NPART + g * 4 + w] = s0;
    } else {
        int p = b - BATCH;
        for (int i = t; i < CW * 256; i += 256) ybuf[0][i >> 8][i & 255] = 0;
        __syncthreads();
        if (t < CW) ybuf[0][t][p * 64 + g * CW + t] = 0x3F80;  // e_{p*64+g*32+t}
        if (t < NPART) partial[(b * NM + 0) * NPART + t] = 0.f;
    }
    __syncthreads();

    int cur = 0;
    for (int j = 1; j <= NSTEPS; ++j) {
        f32x4 acc[4][2] = {};
#pragma unroll
        for (int kc = 0; kc < 8; ++kc) {
            short8 bfr[2];
#pragma unroll
            for (int nt = 0; nt < 2; ++nt)
                bfr[nt] = *(const short8*)&ybuf[cur][nt * 16 + l15][kc * 32 + quad * 8];
#pragma unroll
            for (int mt = 0; mt < 4; ++mt)
#pragma unroll
                for (int nt = 0; nt < 2; ++nt)
                    acc[mt][nt] = __builtin_amdgcn_mfma_f32_16x16x32_bf16(
                        afr[mt][kc], bfr[nt], acc[mt][nt], 0, 0, 0);
        }

        const int nxt = cur ^ 1;
        float d1 = 0.f, d2 = 0.f;
#pragma unroll
        for (int mt = 0; mt < 4; ++mt) {
            int mbase = w * 64 + mt * 16 + quad * 4;   // rows are k-contiguous
#pragma unroll
            for (int nt = 0; nt < 2; ++nt) {
                int col = nt * 16 + l15;
                us4 prev = *(const us4*)&ybuf[cur][col][mbase];
                us4 outv;
#pragma unroll
                for (int r = 0; r < 4; ++r) {
                    float v = acc[mt][nt][r];
                    d1 += bf2f(prev[r]) * v;
                    d2 += v * v;
                    outv[r] = f2bf(v);
                }
                *(us4*)&ybuf[nxt][col][mbase] = outv;
            }
        }
#pragma unroll
        for (int o = 32; o > 0; o >>= 1) {
            d1 += __shfl_down(d1, o);
            d2 += __shfl_down(d2, o);
        }
        if (lane == 0) {
            partial[(b * NM + 2 * j - 1) * NPART + g * 4 + w] = d1;
            partial[(b * NM + 2 * j    ) * NPART + g * 4 + w] = d2;
        }
        cur = nxt;
        __syncthreads();
    }

    // ---- publish; block 0 consumes + solves ----
    __threadfence();
    if (t == 0)
        __hip_atomic_store(&flags[bid], 1u, __ATOMIC_RELEASE, __HIP_MEMORY_SCOPE_AGENT);
    if (bid != 0) return;

    for (int i = t; i < NBLK; i += 256)
        while (__hip_atomic_load(&flags[i], __ATOMIC_RELAXED, __HIP_MEMORY_SCOPE_AGENT) != 1u) {}
    __syncthreads();
    __threadfence();

    for (int pr = t; pr < NB * NM; pr += 256) {
        float s = 0.f;
#pragma unroll
        for (int i = 0; i < NPART; ++i) s += partial[pr * NPART + i];
        msum[pr] = s;
    }
    __syncthreads();

    if (t < BATCH) {
        const int bb = t;
        float mk[NM], Tk[NM];
        float sc = 1.0f;                 // 2^-k rescale (chain used S = 2*Jsym)
#pragma unroll
        for (int k = 0; k < NM; ++k) {
            mk[k] = msum[bb * NM + k] * sc;
            if (k >= 1) {
                float tv = 0.f;
                for (int p = 0; p < PB; ++p) tv += msum[(BATCH + p) * NM + k];
                Tk[k] = tv * sc;
            }
            sc *= 0.5f;
        }
        Tk[0] = 256.0f;
        float tt = 1.0f;
        for (int it = 0; it < 40; ++it) {
            float inv = 1.0f / tt;
            float p1 = inv, S1 = 0.f, S1d = 0.f, S3 = 0.f, S3d = 0.f;
#pragma unroll
            for (int k = 0; k < NM; ++k) {
                float p2 = p1 * inv;
                float p3 = p2 * inv;
                float kp1 = (float)(k + 1);
                S1  += Tk[k] * p1;
                S1d += kp1 * Tk[k] * p2;
                S3  += kp1 * mk[k] * p2;
                S3d += kp1 * (float)(k + 2) * mk[k] * p3;
                p1 = p2;
            }
            float f  = 256.0f - 0.5f * S1 - S3 * (1.0f / 256.0f);
            float df = 0.5f * S1d + S3d * (1.0f / 256.0f);
            if (fabsf(f) <= 1e-4f) break;
            tt -= f / df;
        }
        float inv = 1.0f / tt;
        float logdet = 256.0f * logf(tt);
        float quad = 0.f;
        float p1 = inv, pk = 1.0f;
#pragma unroll
        for (int k = 0; k < NM; ++k) {
            quad += mk[k] * p1;
            if (k >= 1) { pk *= inv; logdet -= Tk[k] / (float)k * pk; }
            p1 *= inv;
        }
        float phi = 256.0f * tt - 0.5f * logdet + quad * (1.0f / 256.0f);
        float afe = -(0.5f * logf((float)M_PI) + phi * (1.0f / 256.0f));
        out[bb] = afe;
        out[BATCH + bb] = tt;
    }
}

// ---------------------------------------------------------------------------
extern "C" void kernel_launch(void* const* d_in, const int* in_sizes, int n_in,
                              void* d_out, int out_size, void* d_ws, size_t ws_size,
                              hipStream_t stream) {
    const float* x  = (const float*)d_in[0];
    const float* Jr = (const float*)d_in[1];
    float* out = (float*)d_out;

    char* base = (char*)d_ws;
    unsigned short* Jsym = (unsigned short*)base;                  // 128 KB
    float* partial = (float*)(base + 131072);                      // 2720 floats
    unsigned int* flags = (unsigned int*)(partial + NB * NM * NPART); // 136 u32

    jbuild_kernel<<<JBLK, 256, 0, stream>>>(Jr, Jsym);
    chain_solve_kernel<<<dim3(CGRP, NB), 256, 0, stream>>>(Jsym, x, partial, flags, out);
}